// Round 13
// baseline (466.898 us; speedup 1.0000x reference)
//
#include <hip/hip_runtime.h>
#include <hip/hip_bf16.h>

// Problem constants (from reference)
#define NN 100000      // nodes
#define NE 1600000     // edges
#define KF 128         // in feats == hidden
#define F1 128         // layer-1 out feats
#define F2 64          // layer-2 out feats

#define NNP 100352                      // padded node count (4B words)
#define BSHIFT 8                        // 256 nodes per bucket
#define NBKT ((NN + 255) >> BSHIFT)     // 391 buckets
#define EPB_H 1024                      // edges per block, phase A
#define EPB 2048                        // edges per block, phase C
#define N4 (NE / 4)                     // 400000 int4 edge-packs

// ---------------------------------------------------------------------------
// Phase A: LDS bucket histogram (by dst>>8) + XCD-privatized src out-degree
// count (8 copies; copy = blockIdx&7 so atomics stay XCD-local under
// round-robin dispatch; any mapping is still correct).
__global__ __launch_bounds__(256) void bkt_hist(
    const int4* __restrict__ src4, const int4* __restrict__ dst4,
    int* __restrict__ cntO8, int* __restrict__ bktCnt)
{
    __shared__ int h[512];
    const int t = threadIdx.x;
    for (int i = t; i < 512; i += 256) h[i] = 0;
    __syncthreads();
    int* cntO = cntO8 + (blockIdx.x & 7) * NNP;
    int i = blockIdx.x * (EPB_H / 4) + t;       // 1 int4-pack per thread
    if (i < N4) {
        int4 s = src4[i]; int4 d = dst4[i];
        atomicAdd(&cntO[s.x], 1); atomicAdd(&cntO[s.y], 1);
        atomicAdd(&cntO[s.z], 1); atomicAdd(&cntO[s.w], 1);
        atomicAdd(&h[d.x >> BSHIFT], 1); atomicAdd(&h[d.y >> BSHIFT], 1);
        atomicAdd(&h[d.z >> BSHIFT], 1); atomicAdd(&h[d.w >> BSHIFT], 1);
    }
    __syncthreads();
    for (int k = t; k < 512; k += 256)
        if (h[k]) atomicAdd(&bktCnt[k], h[k]);
}

// Phase B: exclusive scan of 512 bucket counts -> bases + cursors; row_ptr[NN]=NE
__global__ __launch_bounds__(512) void bkt_scan(
    const int* __restrict__ bktCnt, int* __restrict__ bktBase,
    int* __restrict__ bktCur, int* __restrict__ row_ptr_end)
{
    __shared__ int s[512];
    const int t = threadIdx.x;
    int v = bktCnt[t];
    s[t] = v; __syncthreads();
    for (int off = 1; off < 512; off <<= 1) {
        int x = (t >= off) ? s[t - off] : 0;
        __syncthreads();
        s[t] += x;
        __syncthreads();
    }
    int excl = s[t] - v;
    bktBase[t] = excl;
    bktCur[t] = excl;
    if (t == 511) { bktBase[512] = s[511]; *row_ptr_end = s[511]; }  // == NE
}

// Phase C: scatter edges into bucket-contiguous ebuf as (dst, src)
__global__ __launch_bounds__(256) void bkt_scatter(
    const int4* __restrict__ src4, const int4* __restrict__ dst4,
    int* __restrict__ bktCur, int2* __restrict__ ebuf)
{
    __shared__ int h[512], bb[512], cur[512];
    const int t = threadIdx.x;
    for (int i = t; i < 512; i += 256) h[i] = 0;
    __syncthreads();
    #pragma unroll
    for (int r = 0; r < EPB / 4 / 256; ++r) {
        int i = blockIdx.x * (EPB / 4) + r * 256 + t;
        if (i < N4) {
            int4 d = dst4[i];
            atomicAdd(&h[d.x >> BSHIFT], 1); atomicAdd(&h[d.y >> BSHIFT], 1);
            atomicAdd(&h[d.z >> BSHIFT], 1); atomicAdd(&h[d.w >> BSHIFT], 1);
        }
    }
    __syncthreads();
    for (int i = t; i < 512; i += 256) {
        bb[i] = h[i] ? atomicAdd(&bktCur[i], h[i]) : 0;
        cur[i] = 0;
    }
    __syncthreads();
    #pragma unroll
    for (int r = 0; r < EPB / 4 / 256; ++r) {
        int i = blockIdx.x * (EPB / 4) + r * 256 + t;
        if (i < N4) {
            int4 s = src4[i]; int4 d = dst4[i];
            int b0 = d.x >> BSHIFT, b1 = d.y >> BSHIFT;
            int b2 = d.z >> BSHIFT, b3 = d.w >> BSHIFT;
            int l0 = atomicAdd(&cur[b0], 1);
            int l1 = atomicAdd(&cur[b1], 1);
            int l2 = atomicAdd(&cur[b2], 1);
            int l3 = atomicAdd(&cur[b3], 1);
            ebuf[bb[b0] + l0] = make_int2(d.x, s.x);
            ebuf[bb[b1] + l1] = make_int2(d.y, s.y);
            ebuf[bb[b2] + l2] = make_int2(d.z, s.z);
            ebuf[bb[b3] + l3] = make_int2(d.w, s.w);
        }
    }
}

// Phase D: per-bucket local CSR via LDS count/scan/cursor; writes row_ptr, degI,
// degO (sum of 8 privatized copies -> rsqrt), csr
__global__ __launch_bounds__(256) void bkt_csr(
    const int2* __restrict__ ebuf, const int* __restrict__ bktBase,
    int* __restrict__ row_ptr, float* __restrict__ degI,
    const int* __restrict__ cntO8, float* __restrict__ degO,
    int* __restrict__ csr)
{
    const int b = blockIdx.x;               // 0..NBKT-1
    const int node0 = b << BSHIFT;
    const int ebase = bktBase[b];
    const int ecnt  = bktBase[b + 1] - ebase;
    __shared__ int cnt[256], sc[256], cur[256];
    const int t = threadIdx.x;
    cnt[t] = 0; __syncthreads();
    for (int i = t; i < ecnt; i += 256)
        atomicAdd(&cnt[ebuf[ebase + i].x - node0], 1);
    __syncthreads();
    int v = cnt[t];
    sc[t] = v; __syncthreads();
    for (int off = 1; off < 256; off <<= 1) {
        int x = (t >= off) ? sc[t - off] : 0;
        __syncthreads();
        sc[t] += x;
        __syncthreads();
    }
    int excl = sc[t] - v;
    int node = node0 + t;
    if (node < NN) {
        row_ptr[node] = ebase + excl;
        degI[node] = rsqrtf(fmaxf((float)v, 1.0f));
        int c = 0;
        #pragma unroll
        for (int r = 0; r < 8; ++r) c += cntO8[r * NNP + node];
        degO[node] = rsqrtf(fmaxf((float)c, 1.0f));
    }
    cur[t] = excl; __syncthreads();
    for (int i = t; i < ecnt; i += 256) {
        int2 e = ebuf[ebase + i];
        int slot = atomicAdd(&cur[e.x - node0], 1);
        csr[ebase + slot] = e.y;
    }
}

// ---------------------------------------------------------------------------
// Register-tiled GEMM, bf16 output: Hb[i,j] = bf16(scale[i] * sum_k X[i,k]*W[k,j])
template<int NOUT>
__global__ __launch_bounds__(256) void gemm_rt(
    const float* __restrict__ X, const float* __restrict__ W,
    const float* __restrict__ scale, ushort* __restrict__ Hb, int nrows)
{
    constexpr int K = KF, KC = 32, TN = 8, TM = 4;
    constexpr int CG = NOUT / TN;
    constexpr int RG = 256 / CG;
    constexpr int BM = RG * TM;
    constexpr int XP = KC + 4;

    __shared__ float Xs[2][BM][XP];
    __shared__ float Ws[2][KC][NOUT];

    const int t = threadIdx.x;
    const int cg = t % CG, rg = t / CG;
    const int row0 = blockIdx.x * BM;

    constexpr int XL = BM * (KC / 4) / 256;
    constexpr int WL = KC * (NOUT / 4) / 256;

    float acc[TM][TN];
    #pragma unroll
    for (int i = 0; i < TM; ++i)
        #pragma unroll
        for (int j = 0; j < TN; ++j) acc[i][j] = 0.0f;

    auto load_chunk = [&](int buf, int kc) {
        #pragma unroll
        for (int j = 0; j < XL; ++j) {
            int idx = t + j * 256;
            int r = idx >> 3, kq = idx & 7;
            int gr = min(row0 + r, nrows - 1);
            float4 v = reinterpret_cast<const float4*>(X + (size_t)gr * K + kc)[kq];
            *reinterpret_cast<float4*>(&Xs[buf][r][kq * 4]) = v;
        }
        #pragma unroll
        for (int j = 0; j < WL; ++j) {
            int idx = t + j * 256;
            int kr = idx / (NOUT / 4), c4 = idx % (NOUT / 4);
            float4 v = reinterpret_cast<const float4*>(W + (size_t)(kc + kr) * NOUT)[c4];
            *reinterpret_cast<float4*>(&Ws[buf][kr][c4 * 4]) = v;
        }
    };

    load_chunk(0, 0);
    int buf = 0;
    for (int kc = 0; kc < K; kc += KC) {
        __syncthreads();
        if (kc + KC < K) load_chunk(buf ^ 1, kc + KC);
        #pragma unroll
        for (int k = 0; k < KC; ++k) {
            float w[TN], a[TM];
            *reinterpret_cast<float4*>(&w[0]) =
                *reinterpret_cast<const float4*>(&Ws[buf][k][cg * TN]);
            *reinterpret_cast<float4*>(&w[4]) =
                *reinterpret_cast<const float4*>(&Ws[buf][k][cg * TN + 4]);
            #pragma unroll
            for (int i = 0; i < TM; ++i) a[i] = Xs[buf][rg * TM + i][k];
            #pragma unroll
            for (int i = 0; i < TM; ++i)
                #pragma unroll
                for (int j = 0; j < TN; ++j)
                    acc[i][j] += a[i] * w[j];
        }
        buf ^= 1;
    }

    #pragma unroll
    for (int i = 0; i < TM; ++i) {
        int r = row0 + rg * TM + i;
        if (r < nrows) {
            float s = scale[r];
            uint u[4];
            #pragma unroll
            for (int q = 0; q < 4; ++q) {
                __hip_bfloat162 p = __float22bfloat162_rn(
                    make_float2(acc[i][2 * q] * s, acc[i][2 * q + 1] * s));
                __builtin_memcpy(&u[q], &p, 4);
            }
            uint4 vv = make_uint4(u[0], u[1], u[2], u[3]);
            *reinterpret_cast<uint4*>(Hb + (size_t)r * NOUT + cg * TN) = vv;
        }
    }
}

// ---------------------------------------------------------------------------
// pull aggregation, 128 bf16 feats: one wave per node, lane owns a bfloat162.
template<bool RELU>
__global__ __launch_bounds__(256) void pull128b(
    const ushort* __restrict__ Hb, const int* __restrict__ row_ptr,
    const int* __restrict__ csr, const float* __restrict__ degI,
    const float* __restrict__ b, float* __restrict__ out)
{
    const int node = blockIdx.x * 4 + (threadIdx.x >> 6);
    if (node >= NN) return;
    const int lane = threadIdx.x & 63;
    const int beg = row_ptr[node], end = row_ptr[node + 1];
    const __hip_bfloat162* __restrict__ H2 =
        reinterpret_cast<const __hip_bfloat162*>(Hb);
    float ax = 0.0f, ay = 0.0f;
    int j = beg;
    for (; j + 3 < end; j += 4) {
        int s0 = csr[j], s1 = csr[j + 1], s2 = csr[j + 2], s3 = csr[j + 3];
        float2 f0 = __bfloat1622float2(H2[(size_t)s0 * 64 + lane]);
        float2 f1 = __bfloat1622float2(H2[(size_t)s1 * 64 + lane]);
        float2 f2 = __bfloat1622float2(H2[(size_t)s2 * 64 + lane]);
        float2 f3 = __bfloat1622float2(H2[(size_t)s3 * 64 + lane]);
        ax += f0.x + f1.x + f2.x + f3.x;
        ay += f0.y + f1.y + f2.y + f3.y;
    }
    for (; j < end; ++j) {
        float2 f = __bfloat1622float2(H2[(size_t)csr[j] * 64 + lane]);
        ax += f.x; ay += f.y;
    }
    const float sc = degI[node];
    const float2 bb = reinterpret_cast<const float2*>(b)[lane];
    float ox = ax * sc + bb.x, oy = ay * sc + bb.y;
    if (RELU) { ox = fmaxf(ox, 0.0f); oy = fmaxf(oy, 0.0f); }
    reinterpret_cast<float2*>(out)[(size_t)node * 64 + lane] = make_float2(ox, oy);
}

// pull aggregation, 64 bf16 feats: one wave per node, half-wave per edge.
template<bool RELU>
__global__ __launch_bounds__(256) void pull64b(
    const ushort* __restrict__ Hb, const int* __restrict__ row_ptr,
    const int* __restrict__ csr, const float* __restrict__ degI,
    const float* __restrict__ b, float* __restrict__ out)
{
    const int node = blockIdx.x * 4 + (threadIdx.x >> 6);
    if (node >= NN) return;
    const int lane = threadIdx.x & 63;
    const int half = lane >> 5, l32 = lane & 31;
    const int beg = row_ptr[node], end = row_ptr[node + 1];
    const __hip_bfloat162* __restrict__ H2 =
        reinterpret_cast<const __hip_bfloat162*>(Hb);
    float ax = 0.0f, ay = 0.0f;
    int j = beg;
    for (; j + 3 < end; j += 4) {
        int sA = csr[j + half];
        int sB = csr[j + 2 + half];
        float2 fA = __bfloat1622float2(H2[(size_t)sA * 32 + l32]);
        float2 fB = __bfloat1622float2(H2[(size_t)sB * 32 + l32]);
        ax += fA.x + fB.x; ay += fA.y + fB.y;
    }
    for (; j + 1 < end; j += 2) {
        int s = csr[j + half];
        float2 f = __bfloat1622float2(H2[(size_t)s * 32 + l32]);
        ax += f.x; ay += f.y;
    }
    if (j < end && half == 0) {
        float2 f = __bfloat1622float2(H2[(size_t)csr[j] * 32 + l32]);
        ax += f.x; ay += f.y;
    }
    ax += __shfl_xor(ax, 32);
    ay += __shfl_xor(ay, 32);
    if (half == 0) {
        const float sc = degI[node];
        const float2 bb = reinterpret_cast<const float2*>(b)[l32];
        float ox = ax * sc + bb.x, oy = ay * sc + bb.y;
        if (RELU) { ox = fmaxf(ox, 0.0f); oy = fmaxf(oy, 0.0f); }
        reinterpret_cast<float2*>(out)[(size_t)node * 32 + l32] = make_float2(ox, oy);
    }
}

// ---------------------------------------------------------------------------
extern "C" void kernel_launch(void* const* d_in, const int* in_sizes, int n_in,
                              void* d_out, int out_size, void* d_ws, size_t ws_size,
                              hipStream_t stream)
{
    const float* x   = (const float*)d_in[0];
    const int*   src = (const int*)d_in[1];
    const int*   dst = (const int*)d_in[2];
    const float* W1  = (const float*)d_in[3];
    const float* b1  = (const float*)d_in[4];
    const float* W2  = (const float*)d_in[5];
    const float* b2  = (const float*)d_in[6];
    float* out = (float*)d_out;

    // workspace layout (4B units)
    int* w = (int*)d_ws;
    int*    cntO8   = w;                        // 8 x NNP privatized counts
    int*    bktCnt  = w + 8 * NNP;              // 512 (memset covers cntO8+bktCnt)
    int*    bktBase = w + 8 * NNP + 512;        // 513 (pad 1024)
    int*    bktCur  = w + 8 * NNP + 1536;       // 512
    int*    row_ptr = w + 8 * NNP + 2048;       // NN+1 (pad NNP)
    float*  degO    = (float*)(w + 9 * NNP + 2048);   // NNP
    float*  degI    = (float*)(w + 10 * NNP + 2048);  // NNP
    int*    csr     = w + 11 * NNP + 2048;            // 1.6M
    ushort* h1b     = (ushort*)(w + 11 * NNP + 2048 + 1600000);  // [NN,128] bf16
    int2*   ebuf    = (int2*)h1b;               // aliases h1b (dead before gemm1)
    float*  agg1    = (float*)(w + 11 * NNP + 2048 + 1600000 + 6400000); // [NN,128] f32

    hipMemsetAsync(cntO8, 0, (8 * NNP + 512) * sizeof(int), stream);

    // ---- graph preprocessing: bucket-sorted CSR by dst + degrees ----
    bkt_hist<<<(NE + EPB_H - 1) / EPB_H, 256, 0, stream>>>(
        (const int4*)src, (const int4*)dst, cntO8, bktCnt);
    bkt_scan<<<1, 512, 0, stream>>>(bktCnt, bktBase, bktCur, row_ptr + NN);
    bkt_scatter<<<(NE + EPB - 1) / EPB, 256, 0, stream>>>(
        (const int4*)src, (const int4*)dst, bktCur, ebuf);
    bkt_csr<<<NBKT, 256, 0, stream>>>(ebuf, bktBase, row_ptr, degI, cntO8, degO, csr);

    // ---- layer 1 ----
    gemm_rt<F1><<<(NN + 63) / 64, 256, 0, stream>>>(x, W1, degO, h1b, NN);
    pull128b<true><<<(NN + 3) / 4, 256, 0, stream>>>(h1b, row_ptr, csr, degI, b1, agg1);

    // ---- layer 2 ----
    gemm_rt<F2><<<(NN + 127) / 128, 256, 0, stream>>>(agg1, W2, degO, h1b, NN);
    pull64b<false><<<(NN + 3) / 4, 256, 0, stream>>>(h1b, row_ptr, csr, degI, b2, out);
}

// Round 14
// 382.613 us; speedup vs baseline: 1.2203x; 1.2203x over previous
//
#include <hip/hip_runtime.h>
#include <hip/hip_bf16.h>

// Problem constants (from reference)
#define NN 100000      // nodes
#define NE 1600000     // edges
#define KF 128         // in feats == hidden
#define F1 128         // layer-1 out feats
#define F2 64          // layer-2 out feats

#define NNP 100352                      // padded node count (4B words)
#define BSHIFT 8                        // 256 nodes per bucket
#define NBKT ((NN + 255) >> BSHIFT)     // 391 buckets
#define CAP 5120                        // edges capacity per bucket (mean 4092, +16 sigma)
#define EPB_S 4096                      // edges per block in scatter
#define N4 (NE / 4)                     // 400000 int4 edge-packs

// ---------------------------------------------------------------------------
// init per-bucket write cursors to fixed bases (runs every call)
__global__ __launch_bounds__(512) void init_cur(int* __restrict__ curD,
                                                int* __restrict__ curS)
{
    const int t = threadIdx.x;
    curD[t] = t * CAP;
    curS[t] = t * CAP;
}

// ---------------------------------------------------------------------------
// Single-pass dual bucket scatter: (dst,src) -> ebuf (dst-bucketed),
// src -> sbuf (src-bucketed). LDS histograms; one global cursor atomic per
// nonempty bucket per block. No global histogram / scan kernels needed.
__global__ __launch_bounds__(256) void bkt_scatter2(
    const int4* __restrict__ src4, const int4* __restrict__ dst4,
    int* __restrict__ bktCurD, int* __restrict__ bktCurS,
    int2* __restrict__ ebuf, int* __restrict__ sbuf)
{
    __shared__ int hd[512], hs[512], bbD[512], bbS[512], cd[512], cs[512];
    const int t = threadIdx.x;
    constexpr int PACKS = EPB_S / 4 / 256;   // 4
    for (int i = t; i < 512; i += 256) { hd[i] = 0; hs[i] = 0; }
    __syncthreads();
    #pragma unroll
    for (int r = 0; r < PACKS; ++r) {
        int i = blockIdx.x * (EPB_S / 4) + r * 256 + t;
        if (i < N4) {
            int4 s = src4[i]; int4 d = dst4[i];
            atomicAdd(&hd[d.x >> BSHIFT], 1); atomicAdd(&hd[d.y >> BSHIFT], 1);
            atomicAdd(&hd[d.z >> BSHIFT], 1); atomicAdd(&hd[d.w >> BSHIFT], 1);
            atomicAdd(&hs[s.x >> BSHIFT], 1); atomicAdd(&hs[s.y >> BSHIFT], 1);
            atomicAdd(&hs[s.z >> BSHIFT], 1); atomicAdd(&hs[s.w >> BSHIFT], 1);
        }
    }
    __syncthreads();
    for (int i = t; i < 512; i += 256) {
        bbD[i] = hd[i] ? atomicAdd(&bktCurD[i], hd[i]) : 0;
        bbS[i] = hs[i] ? atomicAdd(&bktCurS[i], hs[i]) : 0;
        cd[i] = 0; cs[i] = 0;
    }
    __syncthreads();
    #pragma unroll
    for (int r = 0; r < PACKS; ++r) {
        int i = blockIdx.x * (EPB_S / 4) + r * 256 + t;
        if (i < N4) {
            int4 s = src4[i]; int4 d = dst4[i];
            int db, sb, l;
            db = d.x >> BSHIFT; l = atomicAdd(&cd[db], 1);
            ebuf[bbD[db] + l] = make_int2(d.x, s.x);
            db = d.y >> BSHIFT; l = atomicAdd(&cd[db], 1);
            ebuf[bbD[db] + l] = make_int2(d.y, s.y);
            db = d.z >> BSHIFT; l = atomicAdd(&cd[db], 1);
            ebuf[bbD[db] + l] = make_int2(d.z, s.z);
            db = d.w >> BSHIFT; l = atomicAdd(&cd[db], 1);
            ebuf[bbD[db] + l] = make_int2(d.w, s.w);
            sb = s.x >> BSHIFT; l = atomicAdd(&cs[sb], 1);
            sbuf[bbS[sb] + l] = s.x;
            sb = s.y >> BSHIFT; l = atomicAdd(&cs[sb], 1);
            sbuf[bbS[sb] + l] = s.y;
            sb = s.z >> BSHIFT; l = atomicAdd(&cs[sb], 1);
            sbuf[bbS[sb] + l] = s.z;
            sb = s.w >> BSHIFT; l = atomicAdd(&cs[sb], 1);
            sbuf[bbS[sb] + l] = s.w;
        }
    }
}

// ---------------------------------------------------------------------------
// Per dst-bucket local CSR via LDS count/scan/cursor; writes row_ptr, row_end,
// degI, csr (bucket-strided by CAP).
__global__ __launch_bounds__(256) void bkt_csr(
    const int2* __restrict__ ebuf, const int* __restrict__ bktCurD,
    int* __restrict__ row_ptr, int* __restrict__ row_end,
    float* __restrict__ degI, int* __restrict__ csr)
{
    const int b = blockIdx.x;               // 0..NBKT-1
    const int node0 = b << BSHIFT;
    const int base = b * CAP;
    const int ecnt = bktCurD[b] - base;
    __shared__ int cnt[256], sc[256], cur[256];
    const int t = threadIdx.x;
    cnt[t] = 0; __syncthreads();
    for (int i = t; i < ecnt; i += 256)
        atomicAdd(&cnt[ebuf[base + i].x - node0], 1);
    __syncthreads();
    int v = cnt[t];
    sc[t] = v; __syncthreads();
    for (int off = 1; off < 256; off <<= 1) {
        int x = (t >= off) ? sc[t - off] : 0;
        __syncthreads();
        sc[t] += x;
        __syncthreads();
    }
    int excl = sc[t] - v;
    int node = node0 + t;
    if (node < NN) {
        row_ptr[node] = base + excl;
        row_end[node] = base + excl + v;
        degI[node] = rsqrtf(fmaxf((float)v, 1.0f));
    }
    cur[t] = excl; __syncthreads();
    for (int i = t; i < ecnt; i += 256) {
        int2 e = ebuf[base + i];
        int slot = atomicAdd(&cur[e.x - node0], 1);
        csr[base + slot] = e.y;
    }
}

// Per src-bucket out-degree count via LDS; degO = rsqrt(max(cnt,1)).
__global__ __launch_bounds__(256) void bkt_degO(
    const int* __restrict__ sbuf, const int* __restrict__ bktCurS,
    float* __restrict__ degO)
{
    const int b = blockIdx.x;
    const int node0 = b << BSHIFT;
    const int base = b * CAP;
    const int ecnt = bktCurS[b] - base;
    __shared__ int cnt[256];
    const int t = threadIdx.x;
    cnt[t] = 0; __syncthreads();
    for (int i = t; i < ecnt; i += 256)
        atomicAdd(&cnt[sbuf[base + i] - node0], 1);
    __syncthreads();
    int node = node0 + t;
    if (node < NN)
        degO[node] = rsqrtf(fmaxf((float)cnt[t], 1.0f));
}

// ---------------------------------------------------------------------------
// Register-tiled GEMM, bf16 output: Hb[i,j] = bf16(scale[i] * sum_k X[i,k]*W[k,j])
template<int NOUT>
__global__ __launch_bounds__(256) void gemm_rt(
    const float* __restrict__ X, const float* __restrict__ W,
    const float* __restrict__ scale, ushort* __restrict__ Hb, int nrows)
{
    constexpr int K = KF, KC = 32, TN = 8, TM = 4;
    constexpr int CG = NOUT / TN;
    constexpr int RG = 256 / CG;
    constexpr int BM = RG * TM;
    constexpr int XP = KC + 4;

    __shared__ float Xs[2][BM][XP];
    __shared__ float Ws[2][KC][NOUT];

    const int t = threadIdx.x;
    const int cg = t % CG, rg = t / CG;
    const int row0 = blockIdx.x * BM;

    constexpr int XL = BM * (KC / 4) / 256;
    constexpr int WL = KC * (NOUT / 4) / 256;

    float acc[TM][TN];
    #pragma unroll
    for (int i = 0; i < TM; ++i)
        #pragma unroll
        for (int j = 0; j < TN; ++j) acc[i][j] = 0.0f;

    auto load_chunk = [&](int buf, int kc) {
        #pragma unroll
        for (int j = 0; j < XL; ++j) {
            int idx = t + j * 256;
            int r = idx >> 3, kq = idx & 7;
            int gr = min(row0 + r, nrows - 1);
            float4 v = reinterpret_cast<const float4*>(X + (size_t)gr * K + kc)[kq];
            *reinterpret_cast<float4*>(&Xs[buf][r][kq * 4]) = v;
        }
        #pragma unroll
        for (int j = 0; j < WL; ++j) {
            int idx = t + j * 256;
            int kr = idx / (NOUT / 4), c4 = idx % (NOUT / 4);
            float4 v = reinterpret_cast<const float4*>(W + (size_t)(kc + kr) * NOUT)[c4];
            *reinterpret_cast<float4*>(&Ws[buf][kr][c4 * 4]) = v;
        }
    };

    load_chunk(0, 0);
    int buf = 0;
    for (int kc = 0; kc < K; kc += KC) {
        __syncthreads();
        if (kc + KC < K) load_chunk(buf ^ 1, kc + KC);
        #pragma unroll
        for (int k = 0; k < KC; ++k) {
            float w[TN], a[TM];
            *reinterpret_cast<float4*>(&w[0]) =
                *reinterpret_cast<const float4*>(&Ws[buf][k][cg * TN]);
            *reinterpret_cast<float4*>(&w[4]) =
                *reinterpret_cast<const float4*>(&Ws[buf][k][cg * TN + 4]);
            #pragma unroll
            for (int i = 0; i < TM; ++i) a[i] = Xs[buf][rg * TM + i][k];
            #pragma unroll
            for (int i = 0; i < TM; ++i)
                #pragma unroll
                for (int j = 0; j < TN; ++j)
                    acc[i][j] += a[i] * w[j];
        }
        buf ^= 1;
    }

    #pragma unroll
    for (int i = 0; i < TM; ++i) {
        int r = row0 + rg * TM + i;
        if (r < nrows) {
            float s = scale[r];
            uint u[4];
            #pragma unroll
            for (int q = 0; q < 4; ++q) {
                __hip_bfloat162 p = __float22bfloat162_rn(
                    make_float2(acc[i][2 * q] * s, acc[i][2 * q + 1] * s));
                __builtin_memcpy(&u[q], &p, 4);
            }
            uint4 vv = make_uint4(u[0], u[1], u[2], u[3]);
            *reinterpret_cast<uint4*>(Hb + (size_t)r * NOUT + cg * TN) = vv;
        }
    }
}

// ---------------------------------------------------------------------------
// pull aggregation, 128 bf16 feats: one wave per node, lane owns a bfloat162.
template<bool RELU>
__global__ __launch_bounds__(256) void pull128b(
    const ushort* __restrict__ Hb, const int* __restrict__ row_ptr,
    const int* __restrict__ row_end, const int* __restrict__ csr,
    const float* __restrict__ degI, const float* __restrict__ b,
    float* __restrict__ out)
{
    const int node = blockIdx.x * 4 + (threadIdx.x >> 6);
    if (node >= NN) return;
    const int lane = threadIdx.x & 63;
    const int beg = row_ptr[node], end = row_end[node];
    const __hip_bfloat162* __restrict__ H2 =
        reinterpret_cast<const __hip_bfloat162*>(Hb);
    float ax = 0.0f, ay = 0.0f;
    int j = beg;
    for (; j + 3 < end; j += 4) {
        int s0 = csr[j], s1 = csr[j + 1], s2 = csr[j + 2], s3 = csr[j + 3];
        float2 f0 = __bfloat1622float2(H2[(size_t)s0 * 64 + lane]);
        float2 f1 = __bfloat1622float2(H2[(size_t)s1 * 64 + lane]);
        float2 f2 = __bfloat1622float2(H2[(size_t)s2 * 64 + lane]);
        float2 f3 = __bfloat1622float2(H2[(size_t)s3 * 64 + lane]);
        ax += f0.x + f1.x + f2.x + f3.x;
        ay += f0.y + f1.y + f2.y + f3.y;
    }
    for (; j < end; ++j) {
        float2 f = __bfloat1622float2(H2[(size_t)csr[j] * 64 + lane]);
        ax += f.x; ay += f.y;
    }
    const float sc = degI[node];
    const float2 bb = reinterpret_cast<const float2*>(b)[lane];
    float ox = ax * sc + bb.x, oy = ay * sc + bb.y;
    if (RELU) { ox = fmaxf(ox, 0.0f); oy = fmaxf(oy, 0.0f); }
    reinterpret_cast<float2*>(out)[(size_t)node * 64 + lane] = make_float2(ox, oy);
}

// pull aggregation, 64 bf16 feats: one wave per node, half-wave per edge.
template<bool RELU>
__global__ __launch_bounds__(256) void pull64b(
    const ushort* __restrict__ Hb, const int* __restrict__ row_ptr,
    const int* __restrict__ row_end, const int* __restrict__ csr,
    const float* __restrict__ degI, const float* __restrict__ b,
    float* __restrict__ out)
{
    const int node = blockIdx.x * 4 + (threadIdx.x >> 6);
    if (node >= NN) return;
    const int lane = threadIdx.x & 63;
    const int half = lane >> 5, l32 = lane & 31;
    const int beg = row_ptr[node], end = row_end[node];
    const __hip_bfloat162* __restrict__ H2 =
        reinterpret_cast<const __hip_bfloat162*>(Hb);
    float ax = 0.0f, ay = 0.0f;
    int j = beg;
    for (; j + 3 < end; j += 4) {
        int sA = csr[j + half];
        int sB = csr[j + 2 + half];
        float2 fA = __bfloat1622float2(H2[(size_t)sA * 32 + l32]);
        float2 fB = __bfloat1622float2(H2[(size_t)sB * 32 + l32]);
        ax += fA.x + fB.x; ay += fA.y + fB.y;
    }
    for (; j + 1 < end; j += 2) {
        int s = csr[j + half];
        float2 f = __bfloat1622float2(H2[(size_t)s * 32 + l32]);
        ax += f.x; ay += f.y;
    }
    if (j < end && half == 0) {
        float2 f = __bfloat1622float2(H2[(size_t)csr[j] * 32 + l32]);
        ax += f.x; ay += f.y;
    }
    ax += __shfl_xor(ax, 32);
    ay += __shfl_xor(ay, 32);
    if (half == 0) {
        const float sc = degI[node];
        const float2 bb = reinterpret_cast<const float2*>(b)[l32];
        float ox = ax * sc + bb.x, oy = ay * sc + bb.y;
        if (RELU) { ox = fmaxf(ox, 0.0f); oy = fmaxf(oy, 0.0f); }
        reinterpret_cast<float2*>(out)[(size_t)node * 32 + l32] = make_float2(ox, oy);
    }
}

// ---------------------------------------------------------------------------
extern "C" void kernel_launch(void* const* d_in, const int* in_sizes, int n_in,
                              void* d_out, int out_size, void* d_ws, size_t ws_size,
                              hipStream_t stream)
{
    const float* x   = (const float*)d_in[0];
    const int*   src = (const int*)d_in[1];
    const int*   dst = (const int*)d_in[2];
    const float* W1  = (const float*)d_in[3];
    const float* b1  = (const float*)d_in[4];
    const float* W2  = (const float*)d_in[5];
    const float* b2  = (const float*)d_in[6];
    float* out = (float*)d_out;

    // workspace layout (4B units)
    int* w = (int*)d_ws;
    int*    bktCurD = w;                        // 512
    int*    bktCurS = w + 512;                  // 512
    int*    row_ptr = w + 1024;                 // NNP
    int*    row_end = w + 1024 + NNP;           // NNP
    float*  degO    = (float*)(w + 1024 + 2 * NNP);   // NNP
    float*  degI    = (float*)(w + 1024 + 3 * NNP);   // NNP
    int*    csr     = w + 1024 + 4 * NNP;             // 512*CAP = 2621440
    ushort* h1b     = (ushort*)(w + 1024 + 4 * NNP + 512 * CAP);  // 12.8M bf16 (6.4M words)
    float*  agg1    = (float*)(w + 1024 + 4 * NNP + 512 * CAP + 6400000); // 12.8M f32
    // preprocessing overlays (dead before gemm1/pull1 write h1b/agg1):
    int2*   ebuf    = (int2*)h1b;               // 512*CAP int2 = 5.24M words < 6.4M
    int*    sbuf    = (int*)agg1;               // 512*CAP ints = 2.62M words < 12.8M

    // ---- graph preprocessing: fixed-capacity dual bucket sort, no global
    //      histogram, no global atomics on per-node counters ----
    init_cur<<<1, 512, 0, stream>>>(bktCurD, bktCurS);
    bkt_scatter2<<<(NE + EPB_S - 1) / EPB_S, 256, 0, stream>>>(
        (const int4*)src, (const int4*)dst, bktCurD, bktCurS, ebuf, sbuf);
    bkt_csr<<<NBKT, 256, 0, stream>>>(ebuf, bktCurD, row_ptr, row_end, degI, csr);
    bkt_degO<<<NBKT, 256, 0, stream>>>(sbuf, bktCurS, degO);

    // ---- layer 1 ----
    gemm_rt<F1><<<(NN + 63) / 64, 256, 0, stream>>>(x, W1, degO, h1b, NN);
    pull128b<true><<<(NN + 3) / 4, 256, 0, stream>>>(
        h1b, row_ptr, row_end, csr, degI, b1, agg1);

    // ---- layer 2 ----
    gemm_rt<F2><<<(NN + 127) / 128, 256, 0, stream>>>(agg1, W2, degO, h1b, NN);
    pull64b<false><<<(NN + 3) / 4, 256, 0, stream>>>(
        h1b, row_ptr, row_end, csr, degI, b2, out);
}